// Round 2
// 1285.922 us; speedup vs baseline: 1.0424x; 1.0424x over previous
//
#include <hip/hip_runtime.h>
#include <hip/hip_bf16.h>

// Problem constants
#define BATCH 4
#define DIMC  64
#define HPD   32
#define NH    8
#define WSZ   16
#define HH    128
#define WW    128
#define BW    256           // BATCH * 64 windows
#define MTOK  256           // WSZ*WSZ
#define IMG   (HH*WW)       // 16384
#define ATTN_ELEMS ((size_t)BW*NH*MTOK*MTOK)   // 134217728
#define OUT_ELEMS  ((size_t)BATCH*DIMC*IMG)    // 4194304

// Workspace float offsets
#define WS_WC    0          // 192 combined 1x3 weights (8 out x 8 in x 3)
#define WS_B2    192        // 8 biases
#define WS_PW    256        // 4096: pw weights TRANSPOSED [c][o]
#define WS_REFL  65536      // 4194304 fp32 reflashed
#define WS_DWOUT (65536 + 4194304)      // also: PV partial chunk 0 (consumed by reduce before dw writes)
#define WS_RES   (65536 + 2*4194304)    // also: PV partial chunk 1 (consumed by reduce before pw writes)

#define CHUNK 128           // m-rows per attn_apply block (2 chunks)

// ---------------- k0: combine ReflashAttn weights + transpose pw ------------
__global__ void prep_kernel(const float* __restrict__ ra_w1,
                            const float* __restrict__ ra_w2,
                            const float* __restrict__ ra_b2,
                            const float* __restrict__ pw_w,
                            float* __restrict__ ws) {
  const int total = 192 + 8 + 4096;
  for (int i = blockIdx.x * blockDim.x + threadIdx.x; i < total;
       i += gridDim.x * blockDim.x) {
    if (i < 192) {
      // Wc[o][j][k] = sum_i w2[o][i] * w1[i][j][0][k]
      int o = i / 24, r = i % 24, j = r / 3, k = r % 3;
      float acc = 0.f;
      #pragma unroll
      for (int t = 0; t < 8; ++t)
        acc += ra_w2[o * 8 + t] * ra_w1[(t * 8 + j) * 3 + k];
      ws[WS_WC + i] = acc;
    } else if (i < 200) {
      ws[WS_B2 + (i - 192)] = ra_b2[i - 192];
    } else {
      int q = i - 200;            // q = o*64 + c in source layout
      int o = q >> 6, c = q & 63;
      ws[WS_PW + c * 64 + o] = pw_w[q];   // store transposed [c][o]
    }
  }
}

// ---------------- k1: FUSED conv1x3+relu+softmax -> attn  AND  PV apply -----
// grid (2 chunks, 256 bw), 512 threads = 8 waves; wave w == head h == staged j-row.
// Each lane owns 4 adjacent columns (c0 = 4*lane); wave spans full n=256 so the
// softmax reduce stays intra-wave. PV output accumulated in registers; the two
// m-chunks write partials that a cheap reduce kernel sums + window-reverses.
__global__ __launch_bounds__(512, 4) void attn_apply_kernel(
    const float* __restrict__ ra, const float* __restrict__ ws,
    const float* __restrict__ lms, float* __restrict__ attn_out,
    float* __restrict__ partial) {
  __shared__ __align__(16) float As[2][8][256];   // double-buffered row staging
  __shared__ __align__(16) float xw[CHUNK][64];   // x window: [m_local][c]

  const int chunk = blockIdx.x;        // 0..1
  const int bw = blockIdx.y;           // 0..255
  const int b = bw >> 6, wi = bw & 63, i1 = wi >> 3, i2 = wi & 7;
  const int t = threadIdx.x;
  const int h = t >> 6;                // wave id == output head == staged input head
  const int lane = t & 63;
  const int c0 = lane << 2;            // 4 adjacent columns per lane

  // per-head combined conv weights (wave-uniform, L2-hot after first block)
  float wj[8][3];
  #pragma unroll
  for (int j = 0; j < 8; ++j)
    #pragma unroll
    for (int k = 0; k < 3; ++k)
      wj[j][k] = ws[WS_WC + (h * 8 + j) * 3 + k];
  const float bias = ws[WS_B2 + h];

  // stage x window values for this chunk's m-range: xw[mi][c]
  for (int i = t; i < CHUNK * 64; i += 512) {
    const int c = i & 63, mi = i >> 6;
    const int m = chunk * CHUNK + mi;
    const int hh = m >> 4, wp = m & 15;
    const int yy = hh * 8 + i1, xx = wp * 8 + i2;   // dilated window partition
    xw[mi][c] = lms[(((size_t)b * 64 + c) * 128 + yy) * 128 + xx];
  }

  // global base of this wave's input-head rows for this chunk
  const float* g0 = ra + ((size_t)(bw * 8 + h) * 256 + (size_t)chunk * CHUNK) * 256;

  // prologue: async-stage row 0 into buffer 0 (lane i -> As[0][h][4i..4i+3])
  __builtin_amdgcn_global_load_lds(
      (const __attribute__((address_space(1))) void*)(g0 + lane * 4),
      (__attribute__((address_space(3))) void*)&As[0][h][0], 16, 0, 0);
  __syncthreads();   // barrier drains vmcnt: xw + row0 visible to all waves

  float4 acc[8];     // acc[d] = 4 output cols for channel d of head h
  #pragma unroll
  for (int d = 0; d < 8; ++d) acc[d] = make_float4(0.f, 0.f, 0.f, 0.f);

  int buf = 0;
  for (int r = 0; r < CHUNK; ++r) {
    // prefetch next row into the other buffer (overlaps with compute below)
    if (r + 1 < CHUNK) {
      __builtin_amdgcn_global_load_lds(
          (const __attribute__((address_space(1))) void*)(g0 + (size_t)(r + 1) * 256 + lane * 4),
          (__attribute__((address_space(3))) void*)&As[buf ^ 1][h][0], 16, 0, 0);
    }

    // --- conv 1x3 over 8 input heads, 4 adjacent cols, edge-sum halo ---
    float v0 = bias, v1 = bias, v2 = bias, v3 = bias;
    float EL = 0.f, ER = 0.f;
    #pragma unroll
    for (int j = 0; j < 8; ++j) {
      const float4 a = *(const float4*)&As[buf][j][c0];   // one b128 per in-head
      const float w0 = wj[j][0], w1 = wj[j][1], w2 = wj[j][2];
      v0 += w1 * a.x + w2 * a.y;
      v1 += w0 * a.x + w1 * a.y + w2 * a.z;
      v2 += w0 * a.y + w1 * a.z + w2 * a.w;
      v3 += w0 * a.z + w1 * a.w;
      EL += w0 * a.w;   // right neighbor's missing w0*A[c0-1] term
      ER += w2 * a.x;   // left neighbor's missing w2*A[c0+4] term
    }
    {
      const float fromL = __shfl_up(EL, 1, 64);
      const float fromR = __shfl_down(ER, 1, 64);
      v0 += (lane == 0) ? 0.f : fromL;     // n=0 halo is zero-pad
      v3 += (lane == 63) ? 0.f : fromR;    // n=255 halo is zero-pad
    }

    // relu + shift-free softmax (values >= 0 and small; shift-invariant)
    v0 = fmaxf(v0, 0.f); v1 = fmaxf(v1, 0.f);
    v2 = fmaxf(v2, 0.f); v3 = fmaxf(v3, 0.f);
    float e0 = __expf(v0), e1 = __expf(v1), e2 = __expf(v2), e3 = __expf(v3);
    float s = (e0 + e1) + (e2 + e3);
    #pragma unroll
    for (int sft = 1; sft < 64; sft <<= 1) s += __shfl_xor(s, sft, 64);
    const float rinv = 1.f / s;
    const float p0 = e0 * rinv, p1 = e1 * rinv, p2 = e2 * rinv, p3 = e3 * rinv;

    // store attn row (required output), one float4 per lane, fully coalesced
    const int m = chunk * CHUNK + r;
    *(float4*)(attn_out + ((size_t)(bw * 8 + h) * 256 + m) * 256 + c0) =
        make_float4(p0, p1, p2, p3);

    // PV accumulate: out[h,d,n] += p[n] * x[h,d,m]   (x via uniform b128 broadcast)
    const float4 xa = *(const float4*)&xw[r][h * 8];
    const float4 xb = *(const float4*)&xw[r][h * 8 + 4];
    const float xv[8] = {xa.x, xa.y, xa.z, xa.w, xb.x, xb.y, xb.z, xb.w};
    #pragma unroll
    for (int d = 0; d < 8; ++d) {
      acc[d].x += p0 * xv[d]; acc[d].y += p1 * xv[d];
      acc[d].z += p2 * xv[d]; acc[d].w += p3 * xv[d];
    }

    __syncthreads();   // prefetch landed everywhere; all waves done reading As[buf]
    buf ^= 1;
  }

  // write PV partial: [chunk][bw][h][d][n]
  float* pbase = partial + (size_t)chunk * OUT_ELEMS +
                 ((size_t)(bw * 8 + h) * 8) * 256 + c0;
  #pragma unroll
  for (int d = 0; d < 8; ++d)
    *(float4*)(pbase + d * 256) = acc[d];
}

// ---------------- k2: sum 2 PV partials + window_reverse -> refl ------------
__global__ __launch_bounds__(256) void reduce_kernel(
    const float* __restrict__ partial, float* __restrict__ refl) {
  const int idx = blockIdx.x * 256 + threadIdx.x;   // 0..4194303 over partial elems
  const int n = idx & 255, d = (idx >> 8) & 7, h = (idx >> 11) & 7, bw = idx >> 14;
  const int b = bw >> 6, wi = bw & 63, i1 = wi >> 3, i2 = wi & 7;
  const int hh = n >> 4, wp = n & 15;
  const int yy = hh * 8 + i1, xx = wp * 8 + i2;
  const float v = partial[idx] + partial[idx + OUT_ELEMS];
  refl[(((size_t)b * 64 + (h * 8 + d)) * 128 + yy) * 128 + xx] = v;
}

// ---------------- k3a: depthwise 3x3 + relu -> dwout ------------------------
__global__ __launch_bounds__(256) void dw_kernel(
    const float* __restrict__ refl, const float* __restrict__ dw_w,
    const float* __restrict__ dw_b, float* __restrict__ dwout) {
  const int idx = blockIdx.x * 256 + threadIdx.x;
  const int x = idx & 127, y = (idx >> 7) & 127;
  const int c = (idx >> 14) & 63, b = idx >> 20;
  const float* in = refl + ((size_t)(b * 64 + c) << 14);
  float w[9];
  #pragma unroll
  for (int k = 0; k < 9; ++k) w[k] = dw_w[c * 9 + k];
  float acc = dw_b[c];
  #pragma unroll
  for (int dy = 0; dy < 3; ++dy) {
    const int yy = y + dy - 1;
    if (yy < 0 || yy > 127) continue;
    #pragma unroll
    for (int dx = 0; dx < 3; ++dx) {
      const int xx = x + dx - 1;
      if (xx < 0 || xx > 127) continue;
      acc += w[dy * 3 + dx] * in[yy * 128 + xx];
    }
  }
  dwout[idx] = fmaxf(acc, 0.f);
}

// ---------------- k3b: 1x1 conv + bias + residual -> res --------------------
__global__ __launch_bounds__(256) void pw_kernel(const float* __restrict__ ws,
                                                 const float* __restrict__ pwb,
                                                 float* __restrict__ res_out) {
  __shared__ __align__(16) float ds[64][64];   // [c][p]
  __shared__ __align__(16) float wsm[64][64];  // [c][o] (already transposed in ws)
  const int tile = blockIdx.x, b = blockIdx.y;
  const int t = threadIdx.x;
  const float* dwout = ws + WS_DWOUT;
  const float* refl = ws + WS_REFL;
  const float* pwT = ws + WS_PW;

  for (int i = t; i < 4096; i += 256) ((float*)wsm)[i] = pwT[i];
  for (int i = t; i < 4096; i += 256) {
    const int c = i >> 6, p = i & 63;
    ds[c][p] = dwout[((size_t)(b * 64 + c) << 14) + tile * 64 + p];
  }
  __syncthreads();

  const int p = t & 63, qo = t >> 6;
  float acc[16];
  #pragma unroll
  for (int i = 0; i < 16; ++i) acc[i] = 0.f;
  for (int c = 0; c < 64; ++c) {
    const float v = ds[c][p];
    const float4* wrow = (const float4*)&wsm[c][0];
    #pragma unroll
    for (int i4 = 0; i4 < 4; ++i4) {
      const float4 w4 = wrow[qo * 4 + i4];
      acc[i4 * 4 + 0] += w4.x * v;
      acc[i4 * 4 + 1] += w4.y * v;
      acc[i4 * 4 + 2] += w4.z * v;
      acc[i4 * 4 + 3] += w4.w * v;
    }
  }
  #pragma unroll
  for (int i = 0; i < 16; ++i) {
    const int o = qo * 16 + i;
    const size_t idx = ((size_t)(b * 64 + o) << 14) + tile * 64 + p;
    res_out[idx] = acc[i] + pwb[o] + refl[idx];
  }
}

// ---------------- k4: fuse 3x3 conv (96->64) + gate -> out (fp32) ----------
__global__ __launch_bounds__(256) void fuse_kernel(
    const float* __restrict__ ws, const float* __restrict__ hp,
    const float* __restrict__ fw, const float* __restrict__ fb,
    float* __restrict__ outp) {
  __shared__ float tile_s[2][324];  // 18x18 halo tile, double buffered
  const int tile = blockIdx.x;      // 64 tiles of 16x16
  const int ocg = blockIdx.y;       // 4 groups of 16 out channels
  const int b = blockIdx.z;
  const int t = threadIdx.x;
  const int ty0 = (tile >> 3) * 16, tx0 = (tile & 7) * 16;
  const int py = t >> 4, px = t & 15;
  const int y = ty0 + py, x = tx0 + px;
  const float* res = ws + WS_RES;
  const float* refl = ws + WS_REFL;

  float acc[16];
  #pragma unroll
  for (int i = 0; i < 16; ++i) acc[i] = 0.f;

  auto load_tile = [&](int ic, int buf) {
    for (int i = t; i < 324; i += 256) {
      const int r = i / 18, cc = i % 18;
      const int gy = ty0 + r - 1, gx = tx0 + cc - 1;
      float v = 0.f;
      if (gy >= 0 && gy < 128 && gx >= 0 && gx < 128) {
        if (ic < 64)
          v = res[(((size_t)b * 64 + ic) * 128 + gy) * 128 + gx];
        else
          v = hp[(((size_t)b * 32 + (ic - 64)) * 128 + gy) * 128 + gx];
      }
      tile_s[buf][i] = v;
    }
  };

  load_tile(0, 0);
  int buf = 0;
  for (int ic = 0; ic < 96; ++ic) {
    __syncthreads();
    if (ic + 1 < 96) load_tile(ic + 1, buf ^ 1);
    float v[9];
    #pragma unroll
    for (int dy = 0; dy < 3; ++dy)
      #pragma unroll
      for (int dx = 0; dx < 3; ++dx)
        v[dy * 3 + dx] = tile_s[buf][(py + dy) * 18 + (px + dx)];
    #pragma unroll
    for (int i = 0; i < 16; ++i) {
      const float* wp = fw + ((size_t)(ocg * 16 + i) * 96 + ic) * 9;
      #pragma unroll
      for (int k = 0; k < 9; ++k) acc[i] += wp[k] * v[k];
    }
    buf ^= 1;
  }

  #pragma unroll
  for (int i = 0; i < 16; ++i) {
    const int o = ocg * 16 + i;
    const size_t idx = (((size_t)b * 64 + o) * 128 + y) * 128 + x;
    outp[idx] = refl[idx] * (acc[i] + fb[o]);
  }
}

extern "C" void kernel_launch(void* const* d_in, const int* in_sizes, int n_in,
                              void* d_out, int out_size, void* d_ws, size_t ws_size,
                              hipStream_t stream) {
  const float* reused = (const float*)d_in[0];
  const float* lms    = (const float*)d_in[1];
  const float* hp     = (const float*)d_in[2];
  const float* ra_w1  = (const float*)d_in[3];
  const float* ra_w2  = (const float*)d_in[4];
  const float* ra_b2  = (const float*)d_in[5];
  const float* dw_w   = (const float*)d_in[6];
  const float* dw_b   = (const float*)d_in[7];
  const float* pw_w   = (const float*)d_in[8];
  const float* pw_b   = (const float*)d_in[9];
  const float* fuse_w = (const float*)d_in[10];
  const float* fuse_b = (const float*)d_in[11];
  float* ws = (float*)d_ws;
  float* out = (float*)d_out;

  prep_kernel<<<17, 256, 0, stream>>>(ra_w1, ra_w2, ra_b2, pw_w, ws);
  // fused attn + PV apply; partials land in WS_DWOUT/WS_RES (free until dw/pw)
  attn_apply_kernel<<<dim3(2, 256), 512, 0, stream>>>(reused, ws, lms, out,
                                                      ws + WS_DWOUT);
  reduce_kernel<<<16384, 256, 0, stream>>>(ws + WS_DWOUT, ws + WS_REFL);
  dw_kernel<<<16384, 256, 0, stream>>>(ws + WS_REFL, dw_w, dw_b, ws + WS_DWOUT);
  pw_kernel<<<dim3(256, 4), 256, 0, stream>>>(ws, pw_b, ws + WS_RES);
  fuse_kernel<<<dim3(64, 4, 4), 256, 0, stream>>>(ws, hp, fuse_w, fuse_b,
                                                  out + ATTN_ELEMS);
}